// Round 1
// baseline (584.094 us; speedup 1.0000x reference)
//
#include <hip/hip_runtime.h>

#define NN 50000
#define NE 500000
#define DD 128

// ALPHA = 0.5 → both the aggregation scale sqrt(ALPHA) and the loop scale
// sqrt(1-ALPHA) are sqrt(0.5).
__device__ __constant__ float SQ_A = 0.70710678118654752440f;

// ---------------------------------------------------------------------------
// Transform: C[n, seg*128 + fhalf*64 + c] where seg 0/1 → hrel[r] (scaled by
// sqrt(alpha)), seg 2 → out = bias + sqrt(1-alpha)*feat@loop_weight.
// Tile: 64 nodes × 64 cols per block, full K=128. LDS = 32KB(W) + 32KB(feat).
// grid.y enumerates (seg,fhalf) pairs starting at seg_base.
// ---------------------------------------------------------------------------
__global__ __launch_bounds__(256)
void transform_kernel(const float* __restrict__ feat,
                      const float* __restrict__ weight,
                      const float* __restrict__ loop_weight,
                      const float* __restrict__ h_bias,
                      float* __restrict__ hrel,
                      float* __restrict__ out,
                      int seg_base)
{
    __shared__ float sW[DD][64];   // [k][col]  32 KB
    __shared__ float sF[64][DD];   // [node][k] 32 KB

    const int tid   = threadIdx.x;
    const int yy    = blockIdx.y + seg_base;
    const int seg   = yy >> 1;     // 0,1 → relation; 2 → loop
    const int fhalf = yy & 1;      // which 64-col half
    const int node0 = blockIdx.x * 64;

    const float* wsrc = (seg < 2) ? (weight + (size_t)seg * DD * DD)
                                  : loop_weight;

    // Stage W half-panel (128 x 64), scaled by sqrt(0.5).
    for (int i = tid; i < DD * 16; i += 256) {     // 128 rows * 16 float4
        int d = i >> 4;
        int c = i & 15;
        float4 w = ((const float4*)(wsrc + (size_t)d * DD + fhalf * 64))[c];
        w.x *= SQ_A; w.y *= SQ_A; w.z *= SQ_A; w.w *= SQ_A;
        ((float4*)&sW[d][0])[c] = w;
    }
    // Stage 64-node feature tile (64 x 128).
    for (int i = tid; i < 64 * 32; i += 256) {     // 64 rows * 32 float4
        int n = i >> 5;
        int c = i & 31;
        float4 v = make_float4(0.f, 0.f, 0.f, 0.f);
        int node = node0 + n;
        if (node < NN) v = ((const float4*)(feat + (size_t)node * DD))[c];
        ((float4*)&sF[n][0])[c] = v;
    }
    __syncthreads();

    const int tf = tid & 15;   // 16 col-groups (float4) → 64 cols
    const int tn = tid >> 4;   // 16 node-groups of 4 → 64 nodes

    float acc[4][4] = {};
    for (int d = 0; d < DD; ++d) {
        float4 w = ((const float4*)&sW[d][0])[tf];
#pragma unroll
        for (int i = 0; i < 4; ++i) {
            float fv = sF[tn * 4 + i][d];
            acc[i][0] += fv * w.x;
            acc[i][1] += fv * w.y;
            acc[i][2] += fv * w.z;
            acc[i][3] += fv * w.w;
        }
    }

    float4 bias = make_float4(0.f, 0.f, 0.f, 0.f);
    float* dbuf;
    if (seg < 2) {
        dbuf = hrel + (size_t)seg * NN * DD;
    } else {
        dbuf = out;
        bias = ((const float4*)(h_bias + fhalf * 64))[tf];
    }
#pragma unroll
    for (int i = 0; i < 4; ++i) {
        int node = node0 + tn * 4 + i;
        if (node < NN) {
            float4 v = make_float4(acc[i][0] + bias.x, acc[i][1] + bias.y,
                                   acc[i][2] + bias.z, acc[i][3] + bias.w);
            ((float4*)(dbuf + (size_t)node * DD + fhalf * 64))[tf] = v;
        }
    }
}

// ---------------------------------------------------------------------------
// Scatter: one wave per edge. Lane reads float2 of hrel[etype][src] and
// atomically adds into out[dst]. hrel rows already carry sqrt(alpha).
// ---------------------------------------------------------------------------
__global__ __launch_bounds__(256)
void scatter_kernel(const int* __restrict__ src, const int* __restrict__ dst,
                    const int* __restrict__ ety,
                    const float* __restrict__ hrel,
                    float* __restrict__ out)
{
    const int e = blockIdx.x * 4 + (threadIdx.x >> 6);
    if (e >= NE) return;
    const int lane = threadIdx.x & 63;
    const int s = src[e];
    const int d = dst[e];
    const int r = ety[e];
    const float2 m = ((const float2*)(hrel + ((size_t)r * NN + s) * DD))[lane];
    float* o = out + (size_t)d * DD + lane * 2;
    atomicAdd(o, m.x);
    atomicAdd(o + 1, m.y);
}

// ---------------------------------------------------------------------------
// Fallback (only if ws too small): fused per-edge matvec, W streamed from
// L2. One wave per edge, grid-stride. Slow but correct.
// ---------------------------------------------------------------------------
__global__ __launch_bounds__(256)
void fused_edge_kernel(const float* __restrict__ feat,
                       const int* __restrict__ src, const int* __restrict__ dst,
                       const int* __restrict__ ety,
                       const float* __restrict__ weight,
                       float* __restrict__ out)
{
    const int wave  = threadIdx.x >> 6;
    const int lane  = threadIdx.x & 63;
    const int nwav  = gridDim.x * 4;
    for (int e = blockIdx.x * 4 + wave; e < NE; e += nwav) {
        const int s = src[e];
        const int d = dst[e];
        const int r = ety[e];
        const float2 fv = ((const float2*)(feat + (size_t)s * DD))[lane];
        const float* W = weight + (size_t)r * DD * DD;
        float a0 = 0.f, a1 = 0.f;
        for (int k = 0; k < 64; ++k) {
            float f0 = __shfl(fv.x, k, 64);   // feat[s][2k]
            float f1 = __shfl(fv.y, k, 64);   // feat[s][2k+1]
            a0 += f0 * W[(size_t)(2 * k) * DD + lane]
                + f1 * W[(size_t)(2 * k + 1) * DD + lane];
            a1 += f0 * W[(size_t)(2 * k) * DD + lane + 64]
                + f1 * W[(size_t)(2 * k + 1) * DD + lane + 64];
        }
        atomicAdd(out + (size_t)d * DD + lane,      SQ_A * a0);
        atomicAdd(out + (size_t)d * DD + lane + 64, SQ_A * a1);
    }
}

extern "C" void kernel_launch(void* const* d_in, const int* in_sizes, int n_in,
                              void* d_out, int out_size, void* d_ws, size_t ws_size,
                              hipStream_t stream)
{
    const float* feat   = (const float*)d_in[0];
    const int*   src    = (const int*)d_in[1];
    const int*   dst    = (const int*)d_in[2];
    const int*   ety    = (const int*)d_in[3];
    const float* weight = (const float*)d_in[4];
    const float* loop_w = (const float*)d_in[5];
    const float* h_bias = (const float*)d_in[6];
    float* out  = (float*)d_out;
    float* hrel = (float*)d_ws;

    const size_t need = (size_t)2 * NN * DD * sizeof(float);   // 51.2 MB
    const int nxb = (NN + 63) / 64;

    if (ws_size >= need) {
        // Main path: transform (h_rel + out-init), then gather/scatter.
        transform_kernel<<<dim3(nxb, 6), 256, 0, stream>>>(
            feat, weight, loop_w, h_bias, hrel, out, 0);
        scatter_kernel<<<dim3((NE + 3) / 4), 256, 0, stream>>>(
            src, dst, ety, hrel, out);
    } else {
        // Fallback: out-init only (seg 2 → grid.y=2 with seg_base=4), then
        // fused per-edge matvec.
        transform_kernel<<<dim3(nxb, 2), 256, 0, stream>>>(
            feat, weight, loop_w, h_bias, hrel, out, 4);
        fused_edge_kernel<<<dim3(2048), 256, 0, stream>>>(
            feat, src, dst, ety, weight, out);
    }
}

// Round 2
// 258.238 us; speedup vs baseline: 2.2618x; 2.2618x over previous
//
#include <hip/hip_runtime.h>

#define NN 50000
#define NE 500000
#define DD 128

// ALPHA = 0.5 → both sqrt(ALPHA) and sqrt(1-ALPHA) are sqrt(0.5).
__device__ __constant__ float SQ_A = 0.70710678118654752440f;

// ---------------------------------------------------------------------------
// Transform: per seg, C[64 nodes x 128 cols] tile.
//   seg 0/1 → hrel[r] = sqrt(a) * feat @ W[r]
//   seg 2   → out     = bias + sqrt(1-a) * feat @ loop_weight
// K staged in two 64-chunks. sF stride 68 → 2-way (free) bank aliasing.
// Each thread: 4 nodes × 8 cols (cols tf*4..+3 and tf*4+64..+67).
// ---------------------------------------------------------------------------
__global__ __launch_bounds__(256)
void transform_kernel(const float* __restrict__ feat,
                      const float* __restrict__ weight,
                      const float* __restrict__ loop_weight,
                      const float* __restrict__ h_bias,
                      float* __restrict__ hrel,
                      float* __restrict__ out,
                      int seg_base)
{
    __shared__ float sW[64][DD];   // [k][col] 32 KB
    __shared__ float sF[64][68];   // [node][k] padded stride → 17 KB

    const int tid   = threadIdx.x;
    const int seg   = blockIdx.y + seg_base;
    const int node0 = blockIdx.x * 64;
    const int tf    = tid & 15;    // col-quad 0..15
    const int tn    = tid >> 4;    // node-group 0..15 (4 nodes each)

    const float* wsrc = (seg < 2) ? (weight + (size_t)seg * DD * DD)
                                  : loop_weight;

    float acc[4][8] = {};

    for (int kk = 0; kk < 2; ++kk) {
        // Stage W rows [kk*64, kk*64+64) x 128 cols, scaled. 2048 float4.
        for (int i = tid; i < 2048; i += 256) {
            int d = i >> 5;
            int c = i & 31;
            float4 w = ((const float4*)(wsrc + (size_t)(kk * 64 + d) * DD))[c];
            w.x *= SQ_A; w.y *= SQ_A; w.z *= SQ_A; w.w *= SQ_A;
            ((float4*)&sW[d][0])[c] = w;
        }
        // Stage feat tile 64 nodes x 64 k. 1024 float4.
        for (int i = tid; i < 1024; i += 256) {
            int n = i >> 4;
            int c = i & 15;
            float4 v = make_float4(0.f, 0.f, 0.f, 0.f);
            int node = node0 + n;
            if (node < NN)
                v = ((const float4*)(feat + (size_t)node * DD + kk * 64))[c];
            *(float4*)&sF[n][c * 4] = v;
        }
        __syncthreads();

#pragma unroll
        for (int dq = 0; dq < 16; ++dq) {
            float4 fv[4];
#pragma unroll
            for (int i = 0; i < 4; ++i)
                fv[i] = *(const float4*)&sF[tn * 4 + i][dq * 4];
            float4 w0[4], w1[4];
#pragma unroll
            for (int j = 0; j < 4; ++j) {
                w0[j] = ((const float4*)&sW[dq * 4 + j][0])[tf];
                w1[j] = ((const float4*)&sW[dq * 4 + j][0])[tf + 16];
            }
#pragma unroll
            for (int i = 0; i < 4; ++i) {
#pragma unroll
                for (int j = 0; j < 4; ++j) {
                    float f = ((const float*)&fv[i])[j];
                    acc[i][0] += f * w0[j].x;
                    acc[i][1] += f * w0[j].y;
                    acc[i][2] += f * w0[j].z;
                    acc[i][3] += f * w0[j].w;
                    acc[i][4] += f * w1[j].x;
                    acc[i][5] += f * w1[j].y;
                    acc[i][6] += f * w1[j].z;
                    acc[i][7] += f * w1[j].w;
                }
            }
        }
        __syncthreads();
    }

    float4 b0 = make_float4(0.f, 0.f, 0.f, 0.f);
    float4 b1 = b0;
    float* dbuf;
    if (seg < 2) {
        dbuf = hrel + (size_t)seg * NN * DD;
    } else {
        dbuf = out;
        b0 = ((const float4*)h_bias)[tf];
        b1 = ((const float4*)h_bias)[tf + 16];
    }
#pragma unroll
    for (int i = 0; i < 4; ++i) {
        int node = node0 + tn * 4 + i;
        if (node < NN) {
            float4 v0 = make_float4(acc[i][0] + b0.x, acc[i][1] + b0.y,
                                    acc[i][2] + b0.z, acc[i][3] + b0.w);
            float4 v1 = make_float4(acc[i][4] + b1.x, acc[i][5] + b1.y,
                                    acc[i][6] + b1.z, acc[i][7] + b1.w);
            ((float4*)(dbuf + (size_t)node * DD))[tf] = v0;
            ((float4*)(dbuf + (size_t)node * DD + 64))[tf] = v1;
        }
    }
}

// ---------------------------------------------------------------------------
// CSR build: zero → histogram → scan(a,b,c) → placement.
// ---------------------------------------------------------------------------
#define OFFS_PAD 50688         // >= 49*1024 (=50176) and >= NN+1

__global__ __launch_bounds__(256)
void zero_kernel(int* __restrict__ offs)
{
    int i = blockIdx.x * 256 + threadIdx.x;
    if (i < OFFS_PAD) offs[i] = 0;
}

__global__ __launch_bounds__(256)
void hist_kernel(const int* __restrict__ dst, int* __restrict__ offs)
{
    int e = blockIdx.x * 256 + threadIdx.x;
    if (e < NE) atomicAdd(&offs[dst[e]], 1);
}

// 49 blocks x 1024: chunk sums.
__global__ __launch_bounds__(1024)
void scan_a_kernel(const int* __restrict__ offs, int* __restrict__ csum)
{
    __shared__ int ws[16];
    int i = blockIdx.x * 1024 + threadIdx.x;
    int v = offs[i];                       // padded region is zeroed
    for (int d = 32; d > 0; d >>= 1) v += __shfl_down(v, d, 64);
    int lane = threadIdx.x & 63, wv = threadIdx.x >> 6;
    if (lane == 0) ws[wv] = v;
    __syncthreads();
    if (threadIdx.x < 16) {
        int s = ws[threadIdx.x];
        for (int d = 8; d > 0; d >>= 1) s += __shfl_down(s, d, 64);
        if (threadIdx.x == 0) csum[blockIdx.x] = s;
    }
}

// 1 block x 64: exclusive scan of 49 chunk sums (in place).
__global__ __launch_bounds__(64)
void scan_b_kernel(int* __restrict__ csum)
{
    int lane = threadIdx.x;
    int v = (lane < 49) ? csum[lane] : 0;
    int inc = v;
    for (int d = 1; d < 64; d <<= 1) {
        int t = __shfl_up(inc, d, 64);
        if (lane >= d) inc += t;
    }
    if (lane < 49) csum[lane] = inc - v;   // exclusive
}

// 49 blocks x 1024: in-place exclusive scan of counts → offs; copy to cursor.
__global__ __launch_bounds__(1024)
void scan_c_kernel(int* __restrict__ offs, int* __restrict__ cursor,
                   const int* __restrict__ csum)
{
    __shared__ int ws[16];
    int i = blockIdx.x * 1024 + threadIdx.x;
    int lane = threadIdx.x & 63, wv = threadIdx.x >> 6;
    int v = offs[i];
    int inc = v;
    for (int d = 1; d < 64; d <<= 1) {
        int t = __shfl_up(inc, d, 64);
        if (lane >= d) inc += t;
    }
    if (lane == 63) ws[wv] = inc;
    __syncthreads();
    if (threadIdx.x < 16) {
        int s = ws[threadIdx.x];
        int sinc = s;
        for (int d = 1; d < 16; d <<= 1) {
            int t = __shfl_up(sinc, d, 64);
            if ((int)threadIdx.x >= d) sinc += t;
        }
        ws[threadIdx.x] = sinc - s;        // exclusive wave base
    }
    __syncthreads();
    int excl = (inc - v) + ws[wv] + csum[blockIdx.x];
    offs[i] = excl;                        // i==NN gets total (=NE) ✓
    if (i < NN) cursor[i] = excl;
}

__global__ __launch_bounds__(256)
void place_kernel(const int* __restrict__ src, const int* __restrict__ dst,
                  const int* __restrict__ ety,
                  int* __restrict__ cursor, int* __restrict__ payload)
{
    int e = blockIdx.x * 256 + threadIdx.x;
    if (e >= NE) return;
    int p = atomicAdd(&cursor[dst[e]], 1);
    payload[p] = (ety[e] << 16) | src[e];
}

// ---------------------------------------------------------------------------
// Gather: one wave per node. acc starts at out[n] (= bias + loop message).
// ---------------------------------------------------------------------------
__global__ __launch_bounds__(256)
void gather_kernel(const int* __restrict__ offs, const int* __restrict__ payload,
                   const float* __restrict__ hrel, float* __restrict__ out)
{
    const int n = blockIdx.x * 4 + (threadIdx.x >> 6);
    if (n >= NN) return;
    const int lane = threadIdx.x & 63;
    const int off0 = offs[n];
    const int off1 = offs[n + 1];
    float* orow = out + (size_t)n * DD;
    float2 acc = ((float2*)orow)[lane];
    int e = off0;
    for (; e + 2 <= off1; e += 2) {
        int p0 = payload[e], p1 = payload[e + 1];
        float2 m0 = ((const float2*)(hrel +
                        ((size_t)(p0 >> 16) * NN + (p0 & 0xffff)) * DD))[lane];
        float2 m1 = ((const float2*)(hrel +
                        ((size_t)(p1 >> 16) * NN + (p1 & 0xffff)) * DD))[lane];
        acc.x += m0.x + m1.x;
        acc.y += m0.y + m1.y;
    }
    if (e < off1) {
        int p0 = payload[e];
        float2 m0 = ((const float2*)(hrel +
                        ((size_t)(p0 >> 16) * NN + (p0 & 0xffff)) * DD))[lane];
        acc.x += m0.x;
        acc.y += m0.y;
    }
    ((float2*)orow)[lane] = acc;
}

// ---------------------------------------------------------------------------
// Tier-2 fallback: atomic scatter (round-1 path).
// ---------------------------------------------------------------------------
__global__ __launch_bounds__(256)
void scatter_kernel(const int* __restrict__ src, const int* __restrict__ dst,
                    const int* __restrict__ ety,
                    const float* __restrict__ hrel,
                    float* __restrict__ out)
{
    const int e = blockIdx.x * 4 + (threadIdx.x >> 6);
    if (e >= NE) return;
    const int lane = threadIdx.x & 63;
    const float2 m = ((const float2*)(hrel +
                        ((size_t)ety[e] * NN + src[e]) * DD))[lane];
    float* o = out + (size_t)dst[e] * DD + lane * 2;
    atomicAdd(o, m.x);
    atomicAdd(o + 1, m.y);
}

// Tier-3 fallback: fused per-edge matvec.
__global__ __launch_bounds__(256)
void fused_edge_kernel(const float* __restrict__ feat,
                       const int* __restrict__ src, const int* __restrict__ dst,
                       const int* __restrict__ ety,
                       const float* __restrict__ weight,
                       float* __restrict__ out)
{
    const int wave  = threadIdx.x >> 6;
    const int lane  = threadIdx.x & 63;
    const int nwav  = gridDim.x * 4;
    for (int e = blockIdx.x * 4 + wave; e < NE; e += nwav) {
        const int s = src[e];
        const int d = dst[e];
        const int r = ety[e];
        const float2 fv = ((const float2*)(feat + (size_t)s * DD))[lane];
        const float* W = weight + (size_t)r * DD * DD;
        float a0 = 0.f, a1 = 0.f;
        for (int k = 0; k < 64; ++k) {
            float f0 = __shfl(fv.x, k, 64);
            float f1 = __shfl(fv.y, k, 64);
            a0 += f0 * W[(size_t)(2 * k) * DD + lane]
                + f1 * W[(size_t)(2 * k + 1) * DD + lane];
            a1 += f0 * W[(size_t)(2 * k) * DD + lane + 64]
                + f1 * W[(size_t)(2 * k + 1) * DD + lane + 64];
        }
        atomicAdd(out + (size_t)d * DD + lane,      SQ_A * a0);
        atomicAdd(out + (size_t)d * DD + lane + 64, SQ_A * a1);
    }
}

extern "C" void kernel_launch(void* const* d_in, const int* in_sizes, int n_in,
                              void* d_out, int out_size, void* d_ws, size_t ws_size,
                              hipStream_t stream)
{
    const float* feat   = (const float*)d_in[0];
    const int*   src    = (const int*)d_in[1];
    const int*   dst    = (const int*)d_in[2];
    const int*   ety    = (const int*)d_in[3];
    const float* weight = (const float*)d_in[4];
    const float* loop_w = (const float*)d_in[5];
    const float* h_bias = (const float*)d_in[6];
    float* out  = (float*)d_out;

    // Workspace layout.
    float* hrel   = (float*)d_ws;
    const size_t hrel_bytes = (size_t)2 * NN * DD * sizeof(float);  // 51.2 MB
    int* offs    = (int*)((char*)d_ws + hrel_bytes);
    int* cursor  = offs + OFFS_PAD;
    int* csum    = cursor + OFFS_PAD;
    int* payload = csum + 64;
    const size_t need_full = hrel_bytes +
        (size_t)(OFFS_PAD * 2 + 64 + NE) * sizeof(int);             // ~53.6 MB

    const int nxb = (NN + 63) / 64;

    if (ws_size >= need_full) {
        transform_kernel<<<dim3(nxb, 3), 256, 0, stream>>>(
            feat, weight, loop_w, h_bias, hrel, out, 0);
        zero_kernel<<<(OFFS_PAD + 255) / 256, 256, 0, stream>>>(offs);
        hist_kernel<<<(NE + 255) / 256, 256, 0, stream>>>(dst, offs);
        scan_a_kernel<<<49, 1024, 0, stream>>>(offs, csum);
        scan_b_kernel<<<1, 64, 0, stream>>>(csum);
        scan_c_kernel<<<49, 1024, 0, stream>>>(offs, cursor, csum);
        place_kernel<<<(NE + 255) / 256, 256, 0, stream>>>(
            src, dst, ety, cursor, payload);
        gather_kernel<<<(NN + 3) / 4, 256, 0, stream>>>(
            offs, payload, hrel, out);
    } else if (ws_size >= hrel_bytes) {
        transform_kernel<<<dim3(nxb, 3), 256, 0, stream>>>(
            feat, weight, loop_w, h_bias, hrel, out, 0);
        scatter_kernel<<<dim3((NE + 3) / 4), 256, 0, stream>>>(
            src, dst, ety, hrel, out);
    } else {
        transform_kernel<<<dim3(nxb, 1), 256, 0, stream>>>(
            feat, weight, loop_w, h_bias, hrel, out, 2);
        fused_edge_kernel<<<dim3(2048), 256, 0, stream>>>(
            feat, src, dst, ety, weight, out);
    }
}

// Round 3
// 226.743 us; speedup vs baseline: 2.5760x; 1.1389x over previous
//
#include <hip/hip_runtime.h>

#define NN 50000
#define NE 500000
#define DD 128

// ALPHA = 0.5 → both sqrt(ALPHA) and sqrt(1-ALPHA) are sqrt(0.5).
__device__ __constant__ float SQ_A = 0.70710678118654752440f;

typedef __attribute__((ext_vector_type(8))) short short8;
typedef __attribute__((ext_vector_type(4))) float float4v;

// float → bf16 bits, round-to-nearest-even.
__device__ inline ushort f2bf(float f)
{
    uint u = __float_as_uint(f);
    u += 0x7fffu + ((u >> 16) & 1u);
    return (ushort)(u >> 16);
}

// ---------------------------------------------------------------------------
// MFMA transform: per seg (grid.y), 64-node × 128-col tile per block.
//   seg 0/1 → hrel[r] = sqrt(a) * feat @ W[r]
//   seg 2   → out     = bias + sqrt(1-a) * feat @ loop_weight
// feat and W are converted to bf16 during LDS staging (scale folded into W).
// LDS: sA[64][136] bf16 (17 KB), sWt[128][136] bf16 transposed (35 KB).
// Stride 136 bf16 = 68 dwords → 2-way (free) bank aliasing on b128 frag reads.
// Wave w computes nodes [w*16, w*16+16) × all 128 cols: 8 MFMA tiles,
// K=128 in 4 steps of 32.
// ---------------------------------------------------------------------------
__global__ __launch_bounds__(256)
void transform_mfma_kernel(const float* __restrict__ feat,
                           const float* __restrict__ weight,
                           const float* __restrict__ loop_weight,
                           const float* __restrict__ h_bias,
                           float* __restrict__ hrel,
                           float* __restrict__ out)
{
    __shared__ ushort sA[64 * 136];
    __shared__ ushort sWt[128 * 136];

    const int tid   = threadIdx.x;
    const int seg   = blockIdx.y;
    const int node0 = blockIdx.x * 64;

    const float* wsrc = (seg < 2) ? (weight + (size_t)seg * DD * DD)
                                  : loop_weight;

    // --- Stage A: 64 nodes × 128 k, fp32→bf16, b128 writes. 1024 ops. ---
#pragma unroll
    for (int i = 0; i < 4; ++i) {
        int flat = tid + i * 256;          // 0..1023
        int n    = flat >> 4;              // node in tile
        int c    = flat & 15;              // 8-elem chunk → k = c*8
        int node = node0 + n;
        float4 v0 = make_float4(0.f, 0.f, 0.f, 0.f), v1 = v0;
        if (node < NN) {
            const float4* fp = (const float4*)(feat + (size_t)node * DD + c * 8);
            v0 = fp[0]; v1 = fp[1];
        }
        uint4 pk;
        pk.x = (uint)f2bf(v0.x) | ((uint)f2bf(v0.y) << 16);
        pk.y = (uint)f2bf(v0.z) | ((uint)f2bf(v0.w) << 16);
        pk.z = (uint)f2bf(v1.x) | ((uint)f2bf(v1.y) << 16);
        pk.w = (uint)f2bf(v1.z) | ((uint)f2bf(v1.w) << 16);
        *(uint4*)&sA[n * 136 + c * 8] = pk;
    }

    // --- Stage W transposed: sWt[col][k] = sqrt(.5)*W[k][col], bf16. ---
    // Per op: two k-rows × 4 cols → 4 b32 writes of (k,k+1) pairs. 2048 ops.
#pragma unroll
    for (int i = 0; i < 8; ++i) {
        int o   = tid + i * 256;           // 0..2047
        int k2  = o >> 5;                  // k pair index, k = k2*2
        int c4  = o & 31;                  // col group, col = c4*4
        const float4 w0 = *(const float4*)(wsrc + (size_t)(k2 * 2)     * DD + c4 * 4);
        const float4 w1 = *(const float4*)(wsrc + (size_t)(k2 * 2 + 1) * DD + c4 * 4);
        const float s = SQ_A;
#pragma unroll
        for (int j = 0; j < 4; ++j) {
            float a = ((const float*)&w0)[j] * s;
            float b = ((const float*)&w1)[j] * s;
            uint pk = (uint)f2bf(a) | ((uint)f2bf(b) << 16);
            *(uint*)&sWt[(c4 * 4 + j) * 136 + k2 * 2] = pk;
        }
    }
    __syncthreads();

    // --- MFMA: wave strip of 16 nodes × 128 cols. ---
    const int wv   = tid >> 6;
    const int lane = tid & 63;
    const int mq   = lane & 15;
    const int quad = lane >> 4;
    const int m_base = wv * 16;

    float4v zero = {0.f, 0.f, 0.f, 0.f};
    float4v acc[8];
#pragma unroll
    for (int ct = 0; ct < 8; ++ct) acc[ct] = zero;

#pragma unroll
    for (int ks = 0; ks < 4; ++ks) {
        short8 a = *(const short8*)&sA[(m_base + mq) * 136 + ks * 32 + quad * 8];
#pragma unroll
        for (int ct = 0; ct < 8; ++ct) {
            short8 b = *(const short8*)&sWt[(ct * 16 + mq) * 136 + ks * 32 + quad * 8];
            acc[ct] = __builtin_amdgcn_mfma_f32_16x16x32_bf16(a, b, acc[ct], 0, 0, 0);
        }
    }

    // --- Epilogue: D row = quad*4+reg, col = ct*16+mq. ---
    float* dbuf = (seg < 2) ? (hrel + (size_t)seg * NN * DD) : out;
#pragma unroll
    for (int ct = 0; ct < 8; ++ct) {
        float bv = (seg == 2) ? h_bias[ct * 16 + mq] : 0.f;
#pragma unroll
        for (int r = 0; r < 4; ++r) {
            int node = node0 + m_base + quad * 4 + r;
            if (node < NN)
                dbuf[(size_t)node * DD + ct * 16 + mq] = acc[ct][r] + bv;
        }
    }
}

// ---------------------------------------------------------------------------
// CSR build: zero → histogram → scan(a,b,c) → placement.
// ---------------------------------------------------------------------------
#define OFFS_PAD 50688         // >= 49*1024 (=50176) and >= NN+1

__global__ __launch_bounds__(256)
void zero_kernel(int* __restrict__ offs)
{
    int i = blockIdx.x * 256 + threadIdx.x;
    if (i < OFFS_PAD) offs[i] = 0;
}

__global__ __launch_bounds__(256)
void hist_kernel(const int* __restrict__ dst, int* __restrict__ offs)
{
    int e = blockIdx.x * 256 + threadIdx.x;
    if (e < NE) atomicAdd(&offs[dst[e]], 1);
}

// 49 blocks x 1024: chunk sums.
__global__ __launch_bounds__(1024)
void scan_a_kernel(const int* __restrict__ offs, int* __restrict__ csum)
{
    __shared__ int ws[16];
    int i = blockIdx.x * 1024 + threadIdx.x;
    int v = offs[i];                       // padded region is zeroed
    for (int d = 32; d > 0; d >>= 1) v += __shfl_down(v, d, 64);
    int lane = threadIdx.x & 63, wv = threadIdx.x >> 6;
    if (lane == 0) ws[wv] = v;
    __syncthreads();
    if (threadIdx.x < 16) {
        int s = ws[threadIdx.x];
        for (int d = 8; d > 0; d >>= 1) s += __shfl_down(s, d, 64);
        if (threadIdx.x == 0) csum[blockIdx.x] = s;
    }
}

// 1 block x 64: exclusive scan of 49 chunk sums (in place).
__global__ __launch_bounds__(64)
void scan_b_kernel(int* __restrict__ csum)
{
    int lane = threadIdx.x;
    int v = (lane < 49) ? csum[lane] : 0;
    int inc = v;
    for (int d = 1; d < 64; d <<= 1) {
        int t = __shfl_up(inc, d, 64);
        if (lane >= d) inc += t;
    }
    if (lane < 49) csum[lane] = inc - v;   // exclusive
}

// 49 blocks x 1024: in-place exclusive scan of counts → offs; copy to cursor.
__global__ __launch_bounds__(1024)
void scan_c_kernel(int* __restrict__ offs, int* __restrict__ cursor,
                   const int* __restrict__ csum)
{
    __shared__ int ws[16];
    int i = blockIdx.x * 1024 + threadIdx.x;
    int lane = threadIdx.x & 63, wv = threadIdx.x >> 6;
    int v = offs[i];
    int inc = v;
    for (int d = 1; d < 64; d <<= 1) {
        int t = __shfl_up(inc, d, 64);
        if (lane >= d) inc += t;
    }
    if (lane == 63) ws[wv] = inc;
    __syncthreads();
    if (threadIdx.x < 16) {
        int s = ws[threadIdx.x];
        int sinc = s;
        for (int d = 1; d < 16; d <<= 1) {
            int t = __shfl_up(sinc, d, 64);
            if ((int)threadIdx.x >= d) sinc += t;
        }
        ws[threadIdx.x] = sinc - s;        // exclusive wave base
    }
    __syncthreads();
    int excl = (inc - v) + ws[wv] + csum[blockIdx.x];
    offs[i] = excl;                        // i==NN gets total (=NE) ✓
    if (i < NN) cursor[i] = excl;
}

__global__ __launch_bounds__(256)
void place_kernel(const int* __restrict__ src, const int* __restrict__ dst,
                  const int* __restrict__ ety,
                  int* __restrict__ cursor, int* __restrict__ payload)
{
    int e = blockIdx.x * 256 + threadIdx.x;
    if (e >= NE) return;
    int p = atomicAdd(&cursor[dst[e]], 1);
    payload[p] = (ety[e] << 16) | src[e];
}

// ---------------------------------------------------------------------------
// Gather: one wave per node. acc starts at out[n] (= bias + loop message).
// ---------------------------------------------------------------------------
__global__ __launch_bounds__(256)
void gather_kernel(const int* __restrict__ offs, const int* __restrict__ payload,
                   const float* __restrict__ hrel, float* __restrict__ out)
{
    const int n = blockIdx.x * 4 + (threadIdx.x >> 6);
    if (n >= NN) return;
    const int lane = threadIdx.x & 63;
    const int off0 = offs[n];
    const int off1 = offs[n + 1];
    float* orow = out + (size_t)n * DD;
    float2 acc = ((float2*)orow)[lane];
    int e = off0;
    for (; e + 2 <= off1; e += 2) {
        int p0 = payload[e], p1 = payload[e + 1];
        float2 m0 = ((const float2*)(hrel +
                        ((size_t)(p0 >> 16) * NN + (p0 & 0xffff)) * DD))[lane];
        float2 m1 = ((const float2*)(hrel +
                        ((size_t)(p1 >> 16) * NN + (p1 & 0xffff)) * DD))[lane];
        acc.x += m0.x + m1.x;
        acc.y += m0.y + m1.y;
    }
    if (e < off1) {
        int p0 = payload[e];
        float2 m0 = ((const float2*)(hrel +
                        ((size_t)(p0 >> 16) * NN + (p0 & 0xffff)) * DD))[lane];
        acc.x += m0.x;
        acc.y += m0.y;
    }
    ((float2*)orow)[lane] = acc;
}

// ---------------------------------------------------------------------------
// Tier-2 fallback: atomic scatter.
// ---------------------------------------------------------------------------
__global__ __launch_bounds__(256)
void scatter_kernel(const int* __restrict__ src, const int* __restrict__ dst,
                    const int* __restrict__ ety,
                    const float* __restrict__ hrel,
                    float* __restrict__ out)
{
    const int e = blockIdx.x * 4 + (threadIdx.x >> 6);
    if (e >= NE) return;
    const int lane = threadIdx.x & 63;
    const float2 m = ((const float2*)(hrel +
                        ((size_t)ety[e] * NN + src[e]) * DD))[lane];
    float* o = out + (size_t)dst[e] * DD + lane * 2;
    atomicAdd(o, m.x);
    atomicAdd(o + 1, m.y);
}

// Tier-3 fallback: fp32 out-init (loop message + bias) + fused per-edge matvec.
__global__ __launch_bounds__(256)
void loop_init_kernel(const float* __restrict__ feat,
                      const float* __restrict__ loop_weight,
                      const float* __restrict__ h_bias,
                      float* __restrict__ out)
{
    // One wave per node: out[n] = bias + sqrt(1-a) * feat[n] @ LW.
    const int n = blockIdx.x * 4 + (threadIdx.x >> 6);
    if (n >= NN) return;
    const int lane = threadIdx.x & 63;
    const float2 fv = ((const float2*)(feat + (size_t)n * DD))[lane];
    float a0 = h_bias[lane], a1 = h_bias[lane + 64];
    for (int k = 0; k < 64; ++k) {
        float f0 = __shfl(fv.x, k, 64);
        float f1 = __shfl(fv.y, k, 64);
        a0 += SQ_A * (f0 * loop_weight[(size_t)(2 * k) * DD + lane]
                    + f1 * loop_weight[(size_t)(2 * k + 1) * DD + lane]);
        a1 += SQ_A * (f0 * loop_weight[(size_t)(2 * k) * DD + lane + 64]
                    + f1 * loop_weight[(size_t)(2 * k + 1) * DD + lane + 64]);
    }
    out[(size_t)n * DD + lane] = a0;
    out[(size_t)n * DD + lane + 64] = a1;
}

__global__ __launch_bounds__(256)
void fused_edge_kernel(const float* __restrict__ feat,
                       const int* __restrict__ src, const int* __restrict__ dst,
                       const int* __restrict__ ety,
                       const float* __restrict__ weight,
                       float* __restrict__ out)
{
    const int wave  = threadIdx.x >> 6;
    const int lane  = threadIdx.x & 63;
    const int nwav  = gridDim.x * 4;
    for (int e = blockIdx.x * 4 + wave; e < NE; e += nwav) {
        const int s = src[e];
        const int d = dst[e];
        const int r = ety[e];
        const float2 fv = ((const float2*)(feat + (size_t)s * DD))[lane];
        const float* W = weight + (size_t)r * DD * DD;
        float a0 = 0.f, a1 = 0.f;
        for (int k = 0; k < 64; ++k) {
            float f0 = __shfl(fv.x, k, 64);
            float f1 = __shfl(fv.y, k, 64);
            a0 += f0 * W[(size_t)(2 * k) * DD + lane]
                + f1 * W[(size_t)(2 * k + 1) * DD + lane];
            a1 += f0 * W[(size_t)(2 * k) * DD + lane + 64]
                + f1 * W[(size_t)(2 * k + 1) * DD + lane + 64];
        }
        atomicAdd(out + (size_t)d * DD + lane,      SQ_A * a0);
        atomicAdd(out + (size_t)d * DD + lane + 64, SQ_A * a1);
    }
}

extern "C" void kernel_launch(void* const* d_in, const int* in_sizes, int n_in,
                              void* d_out, int out_size, void* d_ws, size_t ws_size,
                              hipStream_t stream)
{
    const float* feat   = (const float*)d_in[0];
    const int*   src    = (const int*)d_in[1];
    const int*   dst    = (const int*)d_in[2];
    const int*   ety    = (const int*)d_in[3];
    const float* weight = (const float*)d_in[4];
    const float* loop_w = (const float*)d_in[5];
    const float* h_bias = (const float*)d_in[6];
    float* out  = (float*)d_out;

    // Workspace layout.
    float* hrel   = (float*)d_ws;
    const size_t hrel_bytes = (size_t)2 * NN * DD * sizeof(float);  // 51.2 MB
    int* offs    = (int*)((char*)d_ws + hrel_bytes);
    int* cursor  = offs + OFFS_PAD;
    int* csum    = cursor + OFFS_PAD;
    int* payload = csum + 64;
    const size_t need_full = hrel_bytes +
        (size_t)(OFFS_PAD * 2 + 64 + NE) * sizeof(int);             // ~53.6 MB

    const int nxb = (NN + 63) / 64;

    if (ws_size >= need_full) {
        transform_mfma_kernel<<<dim3(nxb, 3), 256, 0, stream>>>(
            feat, weight, loop_w, h_bias, hrel, out);
        zero_kernel<<<(OFFS_PAD + 255) / 256, 256, 0, stream>>>(offs);
        hist_kernel<<<(NE + 255) / 256, 256, 0, stream>>>(dst, offs);
        scan_a_kernel<<<49, 1024, 0, stream>>>(offs, csum);
        scan_b_kernel<<<1, 64, 0, stream>>>(csum);
        scan_c_kernel<<<49, 1024, 0, stream>>>(offs, cursor, csum);
        place_kernel<<<(NE + 255) / 256, 256, 0, stream>>>(
            src, dst, ety, cursor, payload);
        gather_kernel<<<(NN + 3) / 4, 256, 0, stream>>>(
            offs, payload, hrel, out);
    } else if (ws_size >= hrel_bytes) {
        transform_mfma_kernel<<<dim3(nxb, 3), 256, 0, stream>>>(
            feat, weight, loop_w, h_bias, hrel, out);
        scatter_kernel<<<dim3((NE + 3) / 4), 256, 0, stream>>>(
            src, dst, ety, hrel, out);
    } else {
        loop_init_kernel<<<(NN + 3) / 4, 256, 0, stream>>>(
            feat, loop_w, h_bias, out);
        fused_edge_kernel<<<dim3(2048), 256, 0, stream>>>(
            feat, src, dst, ety, weight, out);
    }
}

// Round 4
// 217.525 us; speedup vs baseline: 2.6852x; 1.0424x over previous
//
#include <hip/hip_runtime.h>

#define NN 50000
#define NPAD 50048          // 782 * 64
#define NE 500000
#define DD 128

// ALPHA = 0.5 → both sqrt(ALPHA) and sqrt(1-ALPHA) are sqrt(0.5).
__device__ __constant__ float SQ_A = 0.70710678118654752440f;

typedef __attribute__((ext_vector_type(8))) short short8;
typedef __attribute__((ext_vector_type(4))) float float4v;

// float → bf16 bits, round-to-nearest-even.
__device__ inline ushort f2bf(float f)
{
    uint u = __float_as_uint(f);
    u += 0x7fffu + ((u >> 16) & 1u);
    return (ushort)(u >> 16);
}
__device__ inline uint pk2(float a, float b)
{
    return (uint)f2bf(a) | ((uint)f2bf(b) << 16);
}

// ---------------------------------------------------------------------------
// Prep: feat fp32 → featb bf16 [NPAD][128] (rows >= NN zeroed);
//       W/loop_w → wtb bf16 transposed+scaled [3][col=128][k=128];
//       zero offs[OFFS_PAD].
// ---------------------------------------------------------------------------
#define OFFS_PAD 50688               // >= 49*1024 and >= NN+1
#define PREP_FEAT (NPAD * 16)        // 16 chunks of 8 elems per row
#define PREP_WTB  (3 * 2048)        // per seg: 16 k-chunks * 128 cols
#define PREP_ZERO (OFFS_PAD / 4)
#define PREP_TASKS (PREP_FEAT + PREP_WTB + PREP_ZERO)

__global__ __launch_bounds__(256)
void prep_kernel(const float* __restrict__ feat,
                 const float* __restrict__ weight,
                 const float* __restrict__ loop_w,
                 ushort* __restrict__ featb,
                 ushort* __restrict__ wtb,
                 int* __restrict__ offs)
{
    int t = blockIdx.x * 256 + threadIdx.x;
    if (t < PREP_FEAT) {
        int row = t >> 4;
        int c   = t & 15;            // k-chunk: elems c*8 .. c*8+7
        float4 v0 = make_float4(0.f, 0.f, 0.f, 0.f), v1 = v0;
        if (row < NN) {
            const float4* p = (const float4*)(feat + (size_t)row * DD + c * 8);
            v0 = p[0]; v1 = p[1];
        }
        uint4 pk;
        pk.x = pk2(v0.x, v0.y); pk.y = pk2(v0.z, v0.w);
        pk.z = pk2(v1.x, v1.y); pk.w = pk2(v1.z, v1.w);
        *(uint4*)&featb[(size_t)row * DD + c * 8] = pk;
    } else if (t < PREP_FEAT + PREP_WTB) {
        int u   = t - PREP_FEAT;
        int seg = u >> 11;           // 0,1 → relations; 2 → loop
        int c   = (u >> 7) & 15;     // k-chunk
        int col = u & 127;           // lanes consecutive in col → coalesced
        const float* wsrc = (seg < 2) ? (weight + (size_t)seg * DD * DD)
                                      : loop_w;
        float v[8];
#pragma unroll
        for (int j = 0; j < 8; ++j)
            v[j] = wsrc[(size_t)(c * 8 + j) * DD + col] * SQ_A;
        uint4 pk;
        pk.x = pk2(v[0], v[1]); pk.y = pk2(v[2], v[3]);
        pk.z = pk2(v[4], v[5]); pk.w = pk2(v[6], v[7]);
        *(uint4*)&wtb[((size_t)seg * DD + col) * DD + c * 8] = pk;
    } else if (t < PREP_TASKS) {
        int u = t - (PREP_FEAT + PREP_WTB);
        ((int4*)offs)[u] = make_int4(0, 0, 0, 0);
    }
}

// ---------------------------------------------------------------------------
// LDS-free MFMA transform. Block = 64 nodes × 128 cols, seg = blockIdx.y.
// Wave w handles all 64 nodes × cols [w*32, w*32+32). B-frags (8×b128) are
// preloaded into registers from wtb; A-frags read per (mt,ks) from featb.
// All frag loads: 16 rows × 64B contiguous per wave-inst (L1/L2-resident).
//   seg 0/1 → hrelb[r] (bf16, sqrt(a) folded into wtb)
//   seg 2   → out = bias + loop message (fp32)
// ---------------------------------------------------------------------------
__global__ __launch_bounds__(256)
void transform_mfma_kernel(const ushort* __restrict__ featb,
                           const ushort* __restrict__ wtb,
                           const float* __restrict__ h_bias,
                           ushort* __restrict__ hrelb,
                           float* __restrict__ out)
{
    const int seg   = blockIdx.y;
    const int node0 = blockIdx.x * 64;
    const int wv    = threadIdx.x >> 6;
    const int lane  = threadIdx.x & 63;
    const int mq    = lane & 15;
    const int quad  = lane >> 4;
    const int col0  = wv * 32;

    const ushort* wseg = wtb + (size_t)seg * DD * DD;

    // Preload B fragments: B[n=mq][k=quad*8+j] per (nt, ks).
    short8 bfrag[2][4];
#pragma unroll
    for (int nt = 0; nt < 2; ++nt)
#pragma unroll
        for (int ks = 0; ks < 4; ++ks)
            bfrag[nt][ks] = *(const short8*)
                &wseg[(size_t)(col0 + nt * 16 + mq) * DD + ks * 32 + quad * 8];

    float4v acc[4][2];
#pragma unroll
    for (int mt = 0; mt < 4; ++mt)
#pragma unroll
        for (int nt = 0; nt < 2; ++nt)
            acc[mt][nt] = (float4v){0.f, 0.f, 0.f, 0.f};

#pragma unroll
    for (int mt = 0; mt < 4; ++mt) {
#pragma unroll
        for (int ks = 0; ks < 4; ++ks) {
            short8 a = *(const short8*)
                &featb[(size_t)(node0 + mt * 16 + mq) * DD + ks * 32 + quad * 8];
#pragma unroll
            for (int nt = 0; nt < 2; ++nt)
                acc[mt][nt] = __builtin_amdgcn_mfma_f32_16x16x32_bf16(
                    a, bfrag[nt][ks], acc[mt][nt], 0, 0, 0);
        }
    }

    // Epilogue. D: row = quad*4 + r, col = mq (per 16x16 tile).
    if (seg < 2) {
        ushort* hb = hrelb + (size_t)seg * NN * DD;
#pragma unroll
        for (int mt = 0; mt < 4; ++mt) {
#pragma unroll
            for (int r = 0; r < 4; ++r) {
                int node = node0 + mt * 16 + quad * 4 + r;
                if (node < NN) {
#pragma unroll
                    for (int nt = 0; nt < 2; ++nt)
                        hb[(size_t)node * DD + col0 + nt * 16 + mq] =
                            f2bf(acc[mt][nt][r]);
                }
            }
        }
    } else {
        float b0 = h_bias[col0 + mq];
        float b1 = h_bias[col0 + 16 + mq];
#pragma unroll
        for (int mt = 0; mt < 4; ++mt) {
#pragma unroll
            for (int r = 0; r < 4; ++r) {
                int node = node0 + mt * 16 + quad * 4 + r;
                if (node < NN) {
                    out[(size_t)node * DD + col0 + mq]      = acc[mt][0][r] + b0;
                    out[(size_t)node * DD + col0 + 16 + mq] = acc[mt][1][r] + b1;
                }
            }
        }
    }
}

// ---------------------------------------------------------------------------
// CSR build: histogram → scan(a,b,c) → placement. (offs zeroed in prep.)
// ---------------------------------------------------------------------------
__global__ __launch_bounds__(256)
void hist_kernel(const int* __restrict__ dst, int* __restrict__ offs)
{
    int e = blockIdx.x * 256 + threadIdx.x;
    if (e < NE) atomicAdd(&offs[dst[e]], 1);
}

// 49 blocks x 1024: chunk sums.
__global__ __launch_bounds__(1024)
void scan_a_kernel(const int* __restrict__ offs, int* __restrict__ csum)
{
    __shared__ int ws[16];
    int i = blockIdx.x * 1024 + threadIdx.x;
    int v = offs[i];                       // padded region is zeroed
    for (int d = 32; d > 0; d >>= 1) v += __shfl_down(v, d, 64);
    int lane = threadIdx.x & 63, wv = threadIdx.x >> 6;
    if (lane == 0) ws[wv] = v;
    __syncthreads();
    if (threadIdx.x < 16) {
        int s = ws[threadIdx.x];
        for (int d = 8; d > 0; d >>= 1) s += __shfl_down(s, d, 64);
        if (threadIdx.x == 0) csum[blockIdx.x] = s;
    }
}

// 1 block x 64: exclusive scan of 49 chunk sums (in place).
__global__ __launch_bounds__(64)
void scan_b_kernel(int* __restrict__ csum)
{
    int lane = threadIdx.x;
    int v = (lane < 49) ? csum[lane] : 0;
    int inc = v;
    for (int d = 1; d < 64; d <<= 1) {
        int t = __shfl_up(inc, d, 64);
        if (lane >= d) inc += t;
    }
    if (lane < 49) csum[lane] = inc - v;   // exclusive
}

// 49 blocks x 1024: in-place exclusive scan of counts → offs; copy to cursor.
__global__ __launch_bounds__(1024)
void scan_c_kernel(int* __restrict__ offs, int* __restrict__ cursor,
                   const int* __restrict__ csum)
{
    __shared__ int ws[16];
    int i = blockIdx.x * 1024 + threadIdx.x;
    int lane = threadIdx.x & 63, wv = threadIdx.x >> 6;
    int v = offs[i];
    int inc = v;
    for (int d = 1; d < 64; d <<= 1) {
        int t = __shfl_up(inc, d, 64);
        if (lane >= d) inc += t;
    }
    if (lane == 63) ws[wv] = inc;
    __syncthreads();
    if (threadIdx.x < 16) {
        int s = ws[threadIdx.x];
        int sinc = s;
        for (int d = 1; d < 16; d <<= 1) {
            int t = __shfl_up(sinc, d, 64);
            if ((int)threadIdx.x >= d) sinc += t;
        }
        ws[threadIdx.x] = sinc - s;        // exclusive wave base
    }
    __syncthreads();
    int excl = (inc - v) + ws[wv] + csum[blockIdx.x];
    offs[i] = excl;                        // i==NN gets total (=NE) ✓
    if (i < NN) cursor[i] = excl;
}

__global__ __launch_bounds__(256)
void place_kernel(const int* __restrict__ src, const int* __restrict__ dst,
                  const int* __restrict__ ety,
                  int* __restrict__ cursor, int* __restrict__ payload)
{
    int e = blockIdx.x * 256 + threadIdx.x;
    if (e >= NE) return;
    int p = atomicAdd(&cursor[dst[e]], 1);
    payload[p] = (ety[e] << 16) | src[e];
}

// ---------------------------------------------------------------------------
// Gather: one wave per node; bf16 messages, fp32 accumulate.
// acc starts at out[n] (= bias + loop message). Lane handles cols 2l, 2l+1.
// ---------------------------------------------------------------------------
__global__ __launch_bounds__(256)
void gather_kernel(const int* __restrict__ offs, const int* __restrict__ payload,
                   const ushort* __restrict__ hrelb, float* __restrict__ out)
{
    const int n = blockIdx.x * 4 + (threadIdx.x >> 6);
    if (n >= NN) return;
    const int lane = threadIdx.x & 63;
    const int e0 = offs[n];
    const int e1 = offs[n + 1];
    float* orow = out + (size_t)n * DD;
    float2 a0 = ((float2*)orow)[lane];
    float2 a1 = make_float2(0.f, 0.f);
    int e = e0;
    for (; e + 2 <= e1; e += 2) {
        int p0 = payload[e], p1 = payload[e + 1];
        uint d0 = *(const uint*)&hrelb[
            ((size_t)(p0 >> 16) * NN + (p0 & 0xffff)) * DD + lane * 2];
        uint d1 = *(const uint*)&hrelb[
            ((size_t)(p1 >> 16) * NN + (p1 & 0xffff)) * DD + lane * 2];
        a0.x += __uint_as_float(d0 << 16);
        a0.y += __uint_as_float(d0 & 0xffff0000u);
        a1.x += __uint_as_float(d1 << 16);
        a1.y += __uint_as_float(d1 & 0xffff0000u);
    }
    if (e < e1) {
        int p0 = payload[e];
        uint d0 = *(const uint*)&hrelb[
            ((size_t)(p0 >> 16) * NN + (p0 & 0xffff)) * DD + lane * 2];
        a0.x += __uint_as_float(d0 << 16);
        a0.y += __uint_as_float(d0 & 0xffff0000u);
    }
    a0.x += a1.x;
    a0.y += a1.y;
    ((float2*)orow)[lane] = a0;
}

// ---------------------------------------------------------------------------
// Tier-2 fallback: atomic scatter from bf16 hrelb.
// ---------------------------------------------------------------------------
__global__ __launch_bounds__(256)
void scatter_kernel(const int* __restrict__ src, const int* __restrict__ dst,
                    const int* __restrict__ ety,
                    const ushort* __restrict__ hrelb,
                    float* __restrict__ out)
{
    const int e = blockIdx.x * 4 + (threadIdx.x >> 6);
    if (e >= NE) return;
    const int lane = threadIdx.x & 63;
    uint d0 = *(const uint*)&hrelb[
        ((size_t)ety[e] * NN + src[e]) * DD + lane * 2];
    float* o = out + (size_t)dst[e] * DD + lane * 2;
    atomicAdd(o,     __uint_as_float(d0 << 16));
    atomicAdd(o + 1, __uint_as_float(d0 & 0xffff0000u));
}

// Tier-3 fallback: fp32 out-init (loop message + bias) + fused per-edge matvec.
__global__ __launch_bounds__(256)
void loop_init_kernel(const float* __restrict__ feat,
                      const float* __restrict__ loop_weight,
                      const float* __restrict__ h_bias,
                      float* __restrict__ out)
{
    const int n = blockIdx.x * 4 + (threadIdx.x >> 6);
    if (n >= NN) return;
    const int lane = threadIdx.x & 63;
    const float2 fv = ((const float2*)(feat + (size_t)n * DD))[lane];
    float a0 = h_bias[lane], a1 = h_bias[lane + 64];
    for (int k = 0; k < 64; ++k) {
        float f0 = __shfl(fv.x, k, 64);
        float f1 = __shfl(fv.y, k, 64);
        a0 += SQ_A * (f0 * loop_weight[(size_t)(2 * k) * DD + lane]
                    + f1 * loop_weight[(size_t)(2 * k + 1) * DD + lane]);
        a1 += SQ_A * (f0 * loop_weight[(size_t)(2 * k) * DD + lane + 64]
                    + f1 * loop_weight[(size_t)(2 * k + 1) * DD + lane + 64]);
    }
    out[(size_t)n * DD + lane] = a0;
    out[(size_t)n * DD + lane + 64] = a1;
}

__global__ __launch_bounds__(256)
void fused_edge_kernel(const float* __restrict__ feat,
                       const int* __restrict__ src, const int* __restrict__ dst,
                       const int* __restrict__ ety,
                       const float* __restrict__ weight,
                       float* __restrict__ out)
{
    const int wave  = threadIdx.x >> 6;
    const int lane  = threadIdx.x & 63;
    const int nwav  = gridDim.x * 4;
    for (int e = blockIdx.x * 4 + wave; e < NE; e += nwav) {
        const int s = src[e];
        const int d = dst[e];
        const int r = ety[e];
        const float2 fv = ((const float2*)(feat + (size_t)s * DD))[lane];
        const float* W = weight + (size_t)r * DD * DD;
        float a0 = 0.f, a1 = 0.f;
        for (int k = 0; k < 64; ++k) {
            float f0 = __shfl(fv.x, k, 64);
            float f1 = __shfl(fv.y, k, 64);
            a0 += f0 * W[(size_t)(2 * k) * DD + lane]
                + f1 * W[(size_t)(2 * k + 1) * DD + lane];
            a1 += f0 * W[(size_t)(2 * k) * DD + lane + 64]
                + f1 * W[(size_t)(2 * k + 1) * DD + lane + 64];
        }
        atomicAdd(out + (size_t)d * DD + lane,      SQ_A * a0);
        atomicAdd(out + (size_t)d * DD + lane + 64, SQ_A * a1);
    }
}

extern "C" void kernel_launch(void* const* d_in, const int* in_sizes, int n_in,
                              void* d_out, int out_size, void* d_ws, size_t ws_size,
                              hipStream_t stream)
{
    const float* feat   = (const float*)d_in[0];
    const int*   src    = (const int*)d_in[1];
    const int*   dst    = (const int*)d_in[2];
    const int*   ety    = (const int*)d_in[3];
    const float* weight = (const float*)d_in[4];
    const float* loop_w = (const float*)d_in[5];
    const float* h_bias = (const float*)d_in[6];
    float* out  = (float*)d_out;

    // Workspace layout (all sections 16B-multiple sized).
    char* p = (char*)d_ws;
    ushort* featb = (ushort*)p;               p += (size_t)NPAD * DD * 2;   // 12.81 MB
    ushort* wtb   = (ushort*)p;               p += (size_t)3 * DD * DD * 2; // 96 KB
    ushort* hrelb = (ushort*)p;               p += (size_t)2 * NN * DD * 2; // 25.6 MB
    int* offs     = (int*)p;                  p += (size_t)OFFS_PAD * 4;
    int* cursor   = (int*)p;                  p += (size_t)OFFS_PAD * 4;
    int* csum     = (int*)p;                  p += 64 * 4;
    int* payload  = (int*)p;                  p += (size_t)NE * 4;
    const size_t need_full = (size_t)(p - (char*)d_ws);                     // ~40.9 MB
    const size_t need_t2   = (size_t)((char*)offs - (char*)d_ws) +
                             (size_t)OFFS_PAD * 4;                          // hrelb path

    const int nxb = NPAD / 64;   // 782

    if (ws_size >= need_full) {
        prep_kernel<<<(PREP_TASKS + 255) / 256, 256, 0, stream>>>(
            feat, weight, loop_w, featb, wtb, offs);
        transform_mfma_kernel<<<dim3(nxb, 3), 256, 0, stream>>>(
            featb, wtb, h_bias, hrelb, out);
        hist_kernel<<<(NE + 255) / 256, 256, 0, stream>>>(dst, offs);
        scan_a_kernel<<<49, 1024, 0, stream>>>(offs, csum);
        scan_b_kernel<<<1, 64, 0, stream>>>(csum);
        scan_c_kernel<<<49, 1024, 0, stream>>>(offs, cursor, csum);
        place_kernel<<<(NE + 255) / 256, 256, 0, stream>>>(
            src, dst, ety, cursor, payload);
        gather_kernel<<<(NN + 3) / 4, 256, 0, stream>>>(
            offs, payload, hrelb, out);
    } else if (ws_size >= need_t2) {
        prep_kernel<<<(PREP_TASKS + 255) / 256, 256, 0, stream>>>(
            feat, weight, loop_w, featb, wtb, offs);
        transform_mfma_kernel<<<dim3(nxb, 3), 256, 0, stream>>>(
            featb, wtb, h_bias, hrelb, out);
        scatter_kernel<<<dim3((NE + 3) / 4), 256, 0, stream>>>(
            src, dst, ety, hrelb, out);
    } else {
        loop_init_kernel<<<(NN + 3) / 4, 256, 0, stream>>>(
            feat, loop_w, h_bias, out);
        fused_edge_kernel<<<dim3(2048), 256, 0, stream>>>(
            feat, src, dst, ety, weight, out);
    }
}